// Round 3
// baseline (305.131 us; speedup 1.0000x reference)
//
#include <hip/hip_runtime.h>
#include <cstddef>

#define NTHREADS 256
#define TROW 8192
#define NROWS 512
#define TILE 1024
#define HALO 256
#define REG 1280           // region length = TILE + HALO
#define CHUNK 5            // REG / NTHREADS (scan ownership)
#define GUARD 64           // zeroed floats in front of Qa/Qd/cl (neg-index reads)
#define FEPS 1e-8f

static_assert(REG == TILE + HALO, "region");
static_assert(CHUNK * NTHREADS == REG, "chunk");
static_assert(4 * NTHREADS == TILE, "ve");

typedef float f32x4 __attribute__((ext_vector_type(4)));

__device__ __forceinline__ float pow_chunk(float b) {
  // b^CHUNK with CHUNK == 5
  float b2 = b * b;
  return b2 * b2 * b;
}

// Aligned vec4 load from a guarded shared array: LDV(buf, v) reads floats
// buf[GUARD + 4v .. GUARD + 4v + 3]  (i.e. arr[4v..4v+3] for arr = buf+GUARD).
#define LDV(buf, v) (((const f32x4*)(buf))[(GUARD / 4) + (v)])

__global__ __launch_bounds__(NTHREADS) void feat_kernel(
    const float* __restrict__ close, float* __restrict__ out) {
  // LDS 26.5 KB -> 6 blocks/CU (binding limit; VGPR kept ~100, no spill).
  __shared__ __align__(16) float QaBuf[GUARD + REG + 4];  // prefix(close)
  __shared__ __align__(16) float QdBuf[GUARD + REG + 4];  // prefix(|d|) -> prefix(sq)
  __shared__ __align__(16) float clBuf[GUARD + REG];
  __shared__ __align__(16) float M[REG];                  // macd
  __shared__ __align__(16) float Sg[REG];                 // signal
  __shared__ float sc[24];
  float* const Qa = QaBuf + GUARD;
  float* const Qd = QdBuf + GUARD;
  float* const cl = clBuf + GUARD;

  const int tid = threadIdx.x;
  const int lane = tid & 63;
  const int wid = tid >> 6;
  const int j = blockIdx.x;   // tile
  const int r = blockIdx.y;   // row
  const int out_start = j * TILE;
  const int s = (j == 0) ? 0 : (out_start - HALO);  // region start (global t)
  const int ob = out_start - s;                      // 0 or HALO (local out base)
  const size_t BT = (size_t)NROWS * TROW;
  const size_t rbase = (size_t)r * TROW + (size_t)s; // out index of local i=0
  const bool first = (j == 0);

  // ---- P1: zero guards + load region (vectorized, coalesced) ----
  {
    const f32x4 z = {0.f, 0.f, 0.f, 0.f};
    if (tid < 16) ((f32x4*)QaBuf)[tid] = z;
    else if (tid < 32) ((f32x4*)QdBuf)[tid - 16] = z;
    else if (tid < 48) ((f32x4*)clBuf)[tid - 32] = z;
    const f32x4* rp4 = reinterpret_cast<const f32x4*>(close + rbase);
    f32x4* cl4 = reinterpret_cast<f32x4*>(clBuf) + GUARD / 4;
    cl4[tid] = rp4[tid];
    if (tid < (REG / 4 - NTHREADS)) cl4[NTHREADS + tid] = rp4[NTHREADS + tid];
  }
  __syncthreads();
  const float c0v = cl[0];  // == close[row][0] when j==0 (pad value)
  const int c0 = tid * CHUNK;
  const int i0 = ob + 4 * tid;       // this thread's 4 consecutive outputs
  const int u = i0 >> 2;             // vec4 index of i0

  const float a12 = 2.f / 13.f, b12 = 11.f / 13.f;
  const float a26 = 2.f / 27.f, b26 = 25.f / 27.f;
  const float a9 = 0.2f, b9 = 0.8f;

  // Chunk caches (statically indexed after unroll -> registers)
  float xk[CHUNK];   // close values of own chunk
  float mreg[CHUNK]; // macd values of own chunk

  // ==== Fused scan pass 1: prefix(close), prefix(|delta|), EMA12, EMA26 ====
  {
    float dk[CHUNK];
    const float xm1 = (c0 == 0) ? 0.f : cl[c0 - 1];
    float prev = xm1;
    float s_c = 0.f, s_a = 0.f, y1 = 0.f, y2 = 0.f;
#pragma unroll
    for (int k = 0; k < CHUNK; ++k) {
      const int i = c0 + k;
      const float x = cl[i];
      xk[k] = x;
      const float d = (i == 0) ? 0.f : fabsf(x - prev);
      dk[k] = d;
      prev = x;
      s_c += x;
      s_a += d;
      if (i == 0) { y1 = x; y2 = x; }   // region-restart init (error decays b^HALO)
      else { y1 = fmaf(b12, y1, a12 * x); y2 = fmaf(b26, y2, a26 * x); }
    }
    float xc = s_c, xa = s_a;
    float A1 = (tid == 0) ? 0.f : pow_chunk(b12);
    float A2 = (tid == 0) ? 0.f : pow_chunk(b26);
    float B1 = y1, B2 = y2;
#pragma unroll
    for (int off = 1; off < 64; off <<= 1) {
      const float pc = __shfl_up(xc, off, 64);
      const float pa = __shfl_up(xa, off, 64);
      const float pA1 = __shfl_up(A1, off, 64), pB1 = __shfl_up(B1, off, 64);
      const float pA2 = __shfl_up(A2, off, 64), pB2 = __shfl_up(B2, off, 64);
      if (lane >= off) {
        xc += pc; xa += pa;
        B1 = fmaf(A1, pB1, B1); A1 *= pA1;
        B2 = fmaf(A2, pB2, B2); A2 *= pA2;
      }
    }
    float eA1 = __shfl_up(A1, 1, 64), eB1 = __shfl_up(B1, 1, 64);
    float eA2 = __shfl_up(A2, 1, 64), eB2 = __shfl_up(B2, 1, 64);
    if (lane == 0) { eA1 = 1.f; eB1 = 0.f; eA2 = 1.f; eB2 = 0.f; }
    if (lane == 63) {
      sc[wid * 6 + 0] = xc; sc[wid * 6 + 1] = xa;
      sc[wid * 6 + 2] = A1; sc[wid * 6 + 3] = B1;
      sc[wid * 6 + 4] = A2; sc[wid * 6 + 5] = B2;
    }
    __syncthreads();
    float woc = 0.f, woa = 0.f, cB1 = 0.f, cB2 = 0.f;
    for (int w = 0; w < wid; ++w) {
      woc += sc[w * 6 + 0];
      woa += sc[w * 6 + 1];
      cB1 = fmaf(sc[w * 6 + 2], cB1, sc[w * 6 + 3]);
      cB2 = fmaf(sc[w * 6 + 4], cB2, sc[w * 6 + 5]);
    }
    float rc = woc + xc - s_c;   // exclusive prefix at chunk start
    float ra = woa + xa - s_a;
    y1 = fmaf(eA1, cB1, eB1);    // EMA carry-in at chunk start
    y2 = fmaf(eA2, cB2, eB2);
    if (tid == 0) { Qa[0] = 0.f; Qd[0] = 0.f; }
#pragma unroll
    for (int k = 0; k < CHUNK; ++k) {
      const int i = c0 + k;
      const float x = xk[k];
      rc += x;     Qa[i + 1] = rc;
      ra += dk[k]; Qd[i + 1] = ra;
      if (i == 0) { y1 = x; y2 = x; }
      else { y1 = fmaf(b12, y1, a12 * x); y2 = fmaf(b26, y2, a26 * x); }
      const float mm = y1 - y2;
      M[i] = mm;
      mreg[k] = mm;
    }
    __syncthreads();
  }

  float* const op = out + rbase + (size_t)i0;
#define ST(f, v) *reinterpret_cast<f32x4*>(op + (size_t)(f) * BT) = (v)

  // ==== Phase A outputs: f0..f8, f9, f16 — dwordx4 stores (1 KB/wave-instr) ====
  {
    const f32x4 a_u  = LDV(QaBuf, u),      a_u1 = LDV(QaBuf, u + 1);
    const f32x4 a_m1 = LDV(QaBuf, u - 1);
    const f32x4 a_m3 = LDV(QaBuf, u - 3),  a_m2 = LDV(QaBuf, u - 2);
    const f32x4 a_m5 = LDV(QaBuf, u - 5),  a_m4 = LDV(QaBuf, u - 4);
    const f32x4 a_m13 = LDV(QaBuf, u - 13), a_m12 = LDV(QaBuf, u - 12);
    const f32x4 cv   = LDV(clBuf, u);
    const float P[4]   = {a_u.y, a_u.z, a_u.w, a_u1.x};       // Qa[i+1]
    const float P5[4]  = {a_m1.x, a_m1.y, a_m1.z, a_m1.w};    // Qa[i-4]
    const float P10[4] = {a_m3.w, a_m2.x, a_m2.y, a_m2.z};    // Qa[i-9]
    const float P20[4] = {a_m5.y, a_m5.z, a_m5.w, a_m4.x};    // Qa[i-19]
    const float P50[4] = {a_m13.w, a_m12.x, a_m12.y, a_m12.z};// Qa[i-49]
    const float cc[4]  = {cv.x, cv.y, cv.z, cv.w};
    float pad5[4] = {0, 0, 0, 0}, pad10[4] = {0, 0, 0, 0};
    float pad20[4] = {0, 0, 0, 0}, pad50[4] = {0, 0, 0, 0};
    if (first) {
#pragma unroll
      for (int k = 0; k < 4; ++k) {
        const float fi = (float)(i0 + k);
        pad5[k]  = fmaxf(4.f - fi, 0.f) * c0v;
        pad10[k] = fmaxf(9.f - fi, 0.f) * c0v;
        pad20[k] = fmaxf(19.f - fi, 0.f) * c0v;
        pad50[k] = fmaxf(49.f - fi, 0.f) * c0v;
      }
    }
    f32x4 v0, v1;
#pragma unroll
    for (int k = 0; k < 4; ++k) {
      const float m = (P[k] - P5[k] + pad5[k]) * 0.2f;
      v0[k] = m; v1[k] = cc[k] / (m + FEPS);
    }
    ST(0, v0); ST(1, v1);
#pragma unroll
    for (int k = 0; k < 4; ++k) {
      const float m = (P[k] - P10[k] + pad10[k]) * 0.1f;
      v0[k] = m; v1[k] = cc[k] / (m + FEPS);
    }
    ST(2, v0); ST(3, v1);
#pragma unroll
    for (int k = 0; k < 4; ++k) {
      const float m = (P[k] - P20[k] + pad20[k]) * 0.05f;
      v0[k] = m; v1[k] = cc[k] / (m + FEPS);
    }
    ST(4, v0); ST(5, v1);
#pragma unroll
    for (int k = 0; k < 4; ++k) {
      const float m = (P[k] - P50[k] + pad50[k]) * 0.02f;
      v0[k] = m; v1[k] = cc[k] / (m + FEPS);
    }
    ST(6, v0); ST(7, v1);

    // RSI + ATR from Qd = prefix(|delta|)
    const f32x4 d_u  = LDV(QdBuf, u),     d_u1 = LDV(QdBuf, u + 1);
    const f32x4 d_m4 = LDV(QdBuf, u - 4), d_m3 = LDV(QdBuf, u - 3);
    const f32x4 c_m4 = LDV(clBuf, u - 4), c_m3 = LDV(clBuf, u - 3);
    const float Pd[4]  = {d_u.y, d_u.z, d_u.w, d_u1.x};    // Qd[i+1]
    const float D13[4] = {d_m4.w, d_m3.x, d_m3.y, d_m3.z}; // Qd[i-13] (guard->0)
    const float C14[4] = {c_m4.z, c_m4.w, c_m3.x, c_m3.y}; // cl[i-14]
#pragma unroll
    for (int k = 0; k < 4; ++k) {
      const int i = i0 + k;
      const float sabs = Pd[k] - D13[k];
      const float cprev = (i < 14) ? c0v : C14[k];  // clamp only reachable on tile 0
      const float sdel = cc[k] - cprev;
      const float g = (sabs + sdel) * (0.5f / 14.f);
      const float l = (sabs - sdel) * (0.5f / 14.f);
      const float rs = g / (l + FEPS);
      v0[k] = 100.f - 100.f / (1.f + rs);
      v1[k] = sabs * (1.f / 14.f);
    }
    ST(8, v0); ST(16, v1);
    ST(9, reinterpret_cast<const f32x4*>(M)[u]);
  }

  // ==== Fused scan pass 2: prefix(sq_diff) + EMA9(macd) ====
  {
    float vq[CHUNK];
    float s_q = 0.f, y9 = 0.f;
#pragma unroll
    for (int k = 0; k < CHUNK; ++k) {
      const int i = c0 + k;
      float v = 0.f;
      if (first || i >= 19) {   // interior tiles: i<19 range unused by outputs
        int al = i - 19;
        float pad = 0.f;
        if (al < 0) { pad = (float)(-al) * c0v; al = 0; }
        const float m20 = (Qa[i + 1] - Qa[al] + pad) * 0.05f;
        const float dd = xk[k] - m20;
        v = dd * dd;
      }
      vq[k] = v;
      s_q += v;
      const float xm = mreg[k];
      if (i == 0) y9 = xm;
      else y9 = fmaf(b9, y9, a9 * xm);
    }
    float xq = s_q;
    float A = (tid == 0) ? 0.f : pow_chunk(b9);
    float Bv = y9;
#pragma unroll
    for (int off = 1; off < 64; off <<= 1) {
      const float pq = __shfl_up(xq, off, 64);
      const float pA = __shfl_up(A, off, 64), pB = __shfl_up(Bv, off, 64);
      if (lane >= off) { xq += pq; Bv = fmaf(A, pB, Bv); A *= pA; }
    }
    float eA = __shfl_up(A, 1, 64), eB = __shfl_up(Bv, 1, 64);
    if (lane == 0) { eA = 1.f; eB = 0.f; }
    if (lane == 63) { sc[wid * 3 + 0] = xq; sc[wid * 3 + 1] = A; sc[wid * 3 + 2] = Bv; }
    __syncthreads();   // also orders Phase-A Qd reads before replay's Qd writes
    float woq = 0.f, cB = 0.f;
    for (int w = 0; w < wid; ++w) {
      woq += sc[w * 3 + 0];
      cB = fmaf(sc[w * 3 + 1], cB, sc[w * 3 + 2]);
    }
    float rq = woq + xq - s_q;
    y9 = fmaf(eA, cB, eB);
    if (tid == 0) Qd[0] = 0.f;
#pragma unroll
    for (int k = 0; k < CHUNK; ++k) {
      const int i = c0 + k;
      rq += vq[k];
      Qd[i + 1] = rq;           // Qd now = prefix(sq_diff); pad terms are 0
      const float xm = mreg[k];
      if (i == 0) y9 = xm;
      else y9 = fmaf(b9, y9, a9 * xm);
      Sg[i] = y9;
    }
    __syncthreads();
  }

  // ==== Phase B outputs: f10..f15 — dwordx4 stores ====
  {
    const f32x4 a_u  = LDV(QaBuf, u),     a_u1 = LDV(QaBuf, u + 1);
    const f32x4 a_m5 = LDV(QaBuf, u - 5), a_m4 = LDV(QaBuf, u - 4);
    const f32x4 q_u  = LDV(QdBuf, u),     q_u1 = LDV(QdBuf, u + 1);
    const f32x4 q_m5 = LDV(QdBuf, u - 5), q_m4 = LDV(QdBuf, u - 4);
    const f32x4 cv   = LDV(clBuf, u);
    const f32x4 mm = reinterpret_cast<const f32x4*>(M)[u];
    const f32x4 sg = reinterpret_cast<const f32x4*>(Sg)[u];
    const float P[4]   = {a_u.y, a_u.z, a_u.w, a_u1.x};    // Qa[i+1]
    const float P20[4] = {a_m5.y, a_m5.z, a_m5.w, a_m4.x}; // Qa[i-19]
    const float Vq[4]  = {q_u.y, q_u.z, q_u.w, q_u1.x};    // Qd'[i+1]
    const float V20[4] = {q_m5.y, q_m5.z, q_m5.w, q_m4.x}; // Qd'[i-19] (guard->0)
    const float cc[4]  = {cv.x, cv.y, cv.z, cv.w};
    float pad20[4] = {0, 0, 0, 0};
    if (first) {
#pragma unroll
      for (int k = 0; k < 4; ++k)
        pad20[k] = fmaxf(19.f - (float)(i0 + k), 0.f) * c0v;
    }
    f32x4 up, mid, lo, pb;
#pragma unroll
    for (int k = 0; k < 4; ++k) {
      const float ma20 = (P[k] - P20[k] + pad20[k]) * 0.05f;
      float vs = Vq[k] - V20[k];
      vs = fmaxf(vs, 0.f);
      const float sd = sqrtf(vs * 0.05f + FEPS);
      up[k] = ma20 + 2.f * sd;
      mid[k] = ma20;
      lo[k] = ma20 - 2.f * sd;
      pb[k] = (cc[k] - lo[k]) / (up[k] - lo[k] + FEPS);
    }
    ST(12, up); ST(13, mid); ST(14, lo); ST(15, pb);
    ST(10, sg);
    ST(11, mm - sg);
  }
#undef ST
}

extern "C" void kernel_launch(void* const* d_in, const int* in_sizes, int n_in,
                              void* d_out, int out_size, void* d_ws, size_t ws_size,
                              hipStream_t stream) {
  (void)in_sizes; (void)n_in; (void)out_size; (void)d_ws; (void)ws_size;
  const float* close = (const float*)d_in[0];  // d_in[1] = volume (unused by reference)
  float* out = (float*)d_out;
  dim3 grid(TROW / TILE, NROWS, 1);
  feat_kernel<<<grid, dim3(NTHREADS, 1, 1), 0, stream>>>(close, out);
}